// Round 1
// baseline (2174.314 us; speedup 1.0000x reference)
//
#include <hip/hip_runtime.h>
#include <hip/hip_bf16.h>
#include <stdint.h>

#define BT 2048
#define HS 2048      // student hidden (H/2)
#define HT 4096      // teacher hidden (H)
#define NVOCAB 32000
#define IGN (-100)

typedef unsigned short u16;
typedef __attribute__((ext_vector_type(4))) float f32x4;
typedef __attribute__((ext_vector_type(8))) short short8;
typedef __attribute__((ext_vector_type(2))) unsigned int u32x2;
typedef __attribute__((ext_vector_type(4))) unsigned int u32x4;

// ---------- helpers ----------
__device__ inline unsigned int pack2_bf16(float a, float b) {
  union { __hip_bfloat162 h; unsigned int u; } cv;
  cv.h = __float22bfloat162_rn(make_float2(a, b));
  return cv.u;
}

__device__ inline void async16(const void* g, void* l) {
  __builtin_amdgcn_global_load_lds(
      (const __attribute__((address_space(1))) void*)g,
      (__attribute__((address_space(3))) void*)l, 16, 0, 0);
}

// ---------- fp32 -> bf16 convert (activations + weights prepass) ----------
__global__ void cvt_f32_bf16(const float4* __restrict__ in, u32x2* __restrict__ out, int n4) {
  int i = blockIdx.x * blockDim.x + threadIdx.x;
  if (i >= n4) return;
  float4 v = in[i];
  u32x2 o;
  o.x = pack2_bf16(v.x, v.y);
  o.y = pack2_bf16(v.z, v.w);
  out[i] = o;
}

// ---------- one NT-GEMM phase: acc[4][4] += A[128 x K] * B[128 x K]^T ----------
// A: bf16 row-major (lda). Staged via global_load_lds (async16).
// B: if WB16, bf16 row-major (ldb) staged via async16 (m97 structure);
//    else fp32 row-major staged via reg->cvt->ds_write (fallback, baseline path).
template <bool WB16>
__device__ inline void gemm_nt(const u16* __restrict__ A, int lda,
                               const void* __restrict__ Bv, int ldb, int K,
                               u16* stA, u16* stB, f32x4 (&acc)[4][4]) {
  const int tid = threadIdx.x;
  const int lane = tid & 63;
  const int w = tid >> 6;
  const int wr = w >> 1, wc = w & 1;
  const int q = lane >> 4, l15 = lane & 15;

  // A async-load mapping: chunk = w*2+c; row = chunk*16 + lane/4; kOff = (lane&3)*8
  const u16* aPtr0 = A + (size_t)(w * 32 + (lane >> 2)) * lda + ((lane & 3) * 8);
  const u16* aPtr1 = aPtr0 + (size_t)16 * lda;
  u16* ldsA0 = stA + (size_t)(w * 2) * 512;      // 512 u16 = 1KB per chunk
  u16* ldsA1 = stA + (size_t)(w * 2 + 1) * 512;

  // B async-load mapping (bf16 path): identical geometry to A
  const u16* Bb = (const u16*)Bv;
  const u16* bPtr0 = Bb + (size_t)(w * 32 + (lane >> 2)) * ldb + ((lane & 3) * 8);
  const u16* bPtr1 = bPtr0 + (size_t)16 * ldb;
  u16* ldsB0 = stB + (size_t)(w * 2) * 512;
  u16* ldsB1 = stB + (size_t)(w * 2 + 1) * 512;

  // B staging mapping (fp32 fallback): row = tid>>1, half = tid&1 covers 16 floats
  const float* Bf = (const float*)Bv;
  const float* bPtrF = Bf + (size_t)(tid >> 1) * ldb + (tid & 1) * 16;
  u16* ldsBw = stB + (tid >> 1) * 32 + (tid & 1) * 16;

  for (int k0 = 0; k0 < K; k0 += 32) {
    __syncthreads();  // previous tile fully consumed
    // A tile (128x32 bf16, 8KB) via async global->LDS
    async16(aPtr0 + k0, ldsA0);
    async16(aPtr1 + k0, ldsA1);
    if constexpr (WB16) {
      // B tile (128x32 bf16, 8KB) via async global->LDS — no VALU, no reg roundtrip
      async16(bPtr0 + k0, ldsB0);
      async16(bPtr1 + k0, ldsB1);
    } else {
      // B tile (128x32 fp32 -> bf16) via registers
      const float4* bp = (const float4*)(bPtrF + k0);
      float4 f0 = bp[0], f1 = bp[1], f2 = bp[2], f3 = bp[3];
      u32x4 w0, w1;
      w0.x = pack2_bf16(f0.x, f0.y); w0.y = pack2_bf16(f0.z, f0.w);
      w0.z = pack2_bf16(f1.x, f1.y); w0.w = pack2_bf16(f1.z, f1.w);
      w1.x = pack2_bf16(f2.x, f2.y); w1.y = pack2_bf16(f2.z, f2.w);
      w1.z = pack2_bf16(f3.x, f3.y); w1.w = pack2_bf16(f3.z, f3.w);
      ((u32x4*)ldsBw)[0] = w0;
      ((u32x4*)ldsBw)[1] = w1;
    }
    __syncthreads();  // tile visible (compiler drains vmcnt+lgkmcnt)

    short8 af[4], bf[4];
#pragma unroll
    for (int f = 0; f < 4; f++)
      af[f] = *(const short8*)&stA[(wr * 64 + f * 16 + l15) * 32 + q * 8];
#pragma unroll
    for (int f = 0; f < 4; f++)
      bf[f] = *(const short8*)&stB[(wc * 64 + f * 16 + l15) * 32 + q * 8];
#pragma unroll
    for (int i = 0; i < 4; i++)
#pragma unroll
      for (int j = 0; j < 4; j++)
        acc[i][j] = __builtin_amdgcn_mfma_f32_16x16x32_bf16(af[i], bf[j], acc[i][j], 0, 0, 0);
  }
}

// ---------- fused dual-GEMM + epilogue ----------
template <bool WB16>
__global__ __launch_bounds__(256) void kmain(
    const u16* __restrict__ sAb, const u16* __restrict__ tAb,
    const void* __restrict__ sW, const void* __restrict__ tW,
    const int* __restrict__ target,
    float* __restrict__ pe, float* __restrict__ ps,
    float* __restrict__ pt, float* __restrict__ pd,
    float* __restrict__ tgtLogit) {
  __shared__ u16 stA[128 * 32];
  __shared__ u16 stB[128 * 32];
  __shared__ u16 sStore[128 * 132];  // [col][row] bf16, row-pitch 132 (pad: bank spread)
  __shared__ int tgtLds[128];

  const int bid = blockIdx.x;
  const int cb = bid >> 4;   // 0..249  (16 consecutive blocks share the weight strip)
  const int rb = bid & 15;   // 0..15
  const int row0 = rb * 128;
  const int col0 = cb * 128;

  const int tid = threadIdx.x;
  const int lane = tid & 63;
  const int w = tid >> 6;
  const int wr = w >> 1, wc = w & 1;
  const int l15 = lane & 15;
  const int q4 = (lane >> 4) << 2;

  if (tid < 128) tgtLds[tid] = target[row0 + tid];

  f32x4 acc[4][4];
#pragma unroll
  for (int i = 0; i < 4; i++)
#pragma unroll
    for (int j = 0; j < 4; j++) acc[i][j] = (f32x4){0.f, 0.f, 0.f, 0.f};

  // ===== student GEMM =====
  {
    const char* bBase;
    if constexpr (WB16)
      bBase = (const char*)sW + (size_t)col0 * HS * sizeof(u16);
    else
      bBase = (const char*)sW + (size_t)col0 * HS * sizeof(float);
    gemm_nt<WB16>(sAb + (size_t)row0 * HS, HS, (const void*)bBase, HS, HS, stA, stB, acc);
  }

  // ===== epilogue 1: expsum, sumsq_s, target logit, stash s (bf16) =====
#pragma unroll
  for (int fr = 0; fr < 4; fr++) {
    const int r0 = wr * 64 + fr * 16 + q4;
    float se[4] = {0.f, 0.f, 0.f, 0.f}, sq[4] = {0.f, 0.f, 0.f, 0.f};
#pragma unroll
    for (int fc = 0; fc < 4; fc++) {
      f32x4 v = acc[fr][fc];
      const int cLoc = wc * 64 + fc * 16 + l15;
      const int cGlob = col0 + cLoc;
      u32x2 pk;
      pk.x = pack2_bf16(v[0], v[1]);
      pk.y = pack2_bf16(v[2], v[3]);
      *(u32x2*)&sStore[cLoc * 132 + r0] = pk;
#pragma unroll
      for (int rg = 0; rg < 4; rg++) {
        float x = v[rg];
        se[rg] += __expf(x);
        sq[rg] += x * x;
        if (tgtLds[r0 + rg] == cGlob) tgtLogit[row0 + r0 + rg] = x;
      }
    }
#pragma unroll
    for (int m = 1; m < 16; m <<= 1) {
#pragma unroll
      for (int rg = 0; rg < 4; rg++) {
        se[rg] += __shfl_xor(se[rg], m, 64);
        sq[rg] += __shfl_xor(sq[rg], m, 64);
      }
    }
    if (l15 == 0) {
      size_t pbase = (size_t)(cb * 2 + wc) * BT + row0 + r0;
#pragma unroll
      for (int rg = 0; rg < 4; rg++) {
        pe[pbase + rg] = se[rg];
        ps[pbase + rg] = sq[rg];
      }
    }
  }

  // ===== teacher GEMM =====
#pragma unroll
  for (int i = 0; i < 4; i++)
#pragma unroll
    for (int j = 0; j < 4; j++) acc[i][j] = (f32x4){0.f, 0.f, 0.f, 0.f};
  {
    const char* bBase;
    if constexpr (WB16)
      bBase = (const char*)tW + (size_t)col0 * HT * sizeof(u16);
    else
      bBase = (const char*)tW + (size_t)col0 * HT * sizeof(float);
    gemm_nt<WB16>(tAb + (size_t)row0 * HT, HT, (const void*)bBase, HT, HT, stA, stB, acc);
  }

  // ===== epilogue 2: sumsq_t, dot(s,t) =====
#pragma unroll
  for (int fr = 0; fr < 4; fr++) {
    const int r0 = wr * 64 + fr * 16 + q4;
    float st[4] = {0.f, 0.f, 0.f, 0.f}, dt[4] = {0.f, 0.f, 0.f, 0.f};
#pragma unroll
    for (int fc = 0; fc < 4; fc++) {
      f32x4 v = acc[fr][fc];
      const int cLoc = wc * 64 + fc * 16 + l15;
      u32x2 p = *(const u32x2*)&sStore[cLoc * 132 + r0];
      float sv[4];
      sv[0] = __uint_as_float(p.x << 16);
      sv[1] = __uint_as_float(p.x & 0xffff0000u);
      sv[2] = __uint_as_float(p.y << 16);
      sv[3] = __uint_as_float(p.y & 0xffff0000u);
#pragma unroll
      for (int rg = 0; rg < 4; rg++) {
        float t = v[rg];
        st[rg] += t * t;
        dt[rg] += sv[rg] * t;
      }
    }
#pragma unroll
    for (int m = 1; m < 16; m <<= 1) {
#pragma unroll
      for (int rg = 0; rg < 4; rg++) {
        st[rg] += __shfl_xor(st[rg], m, 64);
        dt[rg] += __shfl_xor(dt[rg], m, 64);
      }
    }
    if (l15 == 0) {
      size_t pbase = (size_t)(cb * 2 + wc) * BT + row0 + r0;
#pragma unroll
      for (int rg = 0; rg < 4; rg++) {
        pt[pbase + rg] = st[rg];
        pd[pbase + rg] = dt[rg];
      }
    }
  }
}

// ---------- per-row reduce over 500 column slabs ----------
__global__ void kreduce(const float* __restrict__ pe, const float* __restrict__ ps,
                        const float* __restrict__ pt, const float* __restrict__ pd,
                        const float* __restrict__ tgtLogit, const int* __restrict__ target,
                        float* __restrict__ scal) {
  int row = blockIdx.x * blockDim.x + threadIdx.x;  // 2048 threads
  float se = 0.f, ss = 0.f, st = 0.f, dt = 0.f;
  for (int j = 0; j < 500; j++) {
    int idx = j * BT + row;
    se += pe[idx];
    ss += ps[idx];
    st += pt[idx];
    dt += pd[idx];
  }
  int tgt = target[row];
  bool valid = (tgt != IGN);
  float hard = valid ? (__logf(se) - tgtLogit[row]) : 0.f;
  float cosv = dt * rsqrtf(ss + 1e-12f) * rsqrtf(st + 1e-12f);
  float soft = 1.f - cosv;
  float nv = valid ? 1.f : 0.f;
  for (int m = 1; m < 64; m <<= 1) {
    hard += __shfl_xor(hard, m, 64);
    soft += __shfl_xor(soft, m, 64);
    nv += __shfl_xor(nv, m, 64);
  }
  if ((threadIdx.x & 63) == 0) {
    atomicAdd(&scal[0], hard);
    atomicAdd(&scal[1], soft);
    atomicAdd(&scal[2], nv);
  }
}

__global__ void kfinal(const float* __restrict__ scal, float* __restrict__ out) {
  float nv = scal[2];
  out[0] = 0.5f * scal[0] / nv + 0.5f * scal[1] / nv;
}

// ---------- launch ----------
extern "C" void kernel_launch(void* const* d_in, const int* in_sizes, int n_in,
                              void* d_out, int out_size, void* d_ws, size_t ws_size,
                              hipStream_t stream) {
  const float* student = (const float*)d_in[0];
  const float* teacher = (const float*)d_in[1];
  const int* target = (const int*)d_in[2];
  const float* sW = (const float*)d_in[3];
  const float* tW = (const float*)d_in[4];
  float* out = (float*)d_out;

  char* ws = (char*)d_ws;

  // big-workspace layout (bytes):
  //   sAb : 0           (2048x2048 bf16 =   8,388,608)
  //   tAb : 8,388,608   (2048x4096 bf16 =  16,777,216)
  //   sWb : 25,165,824  (32000x2048 bf16 = 131,072,000)
  //   tWb : 156,237,824 (32000x4096 bf16 = 262,144,000)
  //   pe/ps/pt/pd : 4 x 4,096,000 at 418,381,824
  //   tgtLogit : 434,765,824 (2048 f32)
  //   scal : 434,774,016 (3 f32)
  const size_t NEED = 434774028;

  if (ws_size >= NEED) {
    u16* sAb = (u16*)(ws);
    u16* tAb = (u16*)(ws + 8388608);
    u16* sWb = (u16*)(ws + 25165824);
    u16* tWb = (u16*)(ws + 156237824);
    float* pe = (float*)(ws + 418381824);
    float* ps = (float*)(ws + 422477824);
    float* pt = (float*)(ws + 426573824);
    float* pd = (float*)(ws + 430669824);
    float* tgtLogit = (float*)(ws + 434765824);
    float* scal = (float*)(ws + 434774016);

    hipMemsetAsync(scal, 0, 3 * sizeof(float), stream);

    {
      int n4 = BT * HS / 4;  // 1,048,576
      cvt_f32_bf16<<<(n4 + 255) / 256, 256, 0, stream>>>((const float4*)student, (u32x2*)sAb, n4);
    }
    {
      int n4 = BT * HT / 4;  // 2,097,152
      cvt_f32_bf16<<<(n4 + 255) / 256, 256, 0, stream>>>((const float4*)teacher, (u32x2*)tAb, n4);
    }
    {
      int n4 = NVOCAB * HS / 4;  // 16,384,000
      cvt_f32_bf16<<<(n4 + 255) / 256, 256, 0, stream>>>((const float4*)sW, (u32x2*)sWb, n4);
    }
    {
      int n4 = NVOCAB * HT / 4;  // 32,768,000
      cvt_f32_bf16<<<(n4 + 255) / 256, 256, 0, stream>>>((const float4*)tW, (u32x2*)tWb, n4);
    }

    kmain<true><<<dim3(4000), dim3(256), 0, stream>>>(
        sAb, tAb, (const void*)sWb, (const void*)tWb, target, pe, ps, pt, pd, tgtLogit);
    kreduce<<<dim3(8), dim3(256), 0, stream>>>(pe, ps, pt, pd, tgtLogit, target, scal);
    kfinal<<<dim3(1), dim3(1), 0, stream>>>(scal, out);
  } else {
    // fallback: verified baseline layout (fp32 weights consumed in-kernel)
    u16* sAb = (u16*)(ws);
    u16* tAb = (u16*)(ws + 8388608);
    float* pe = (float*)(ws + 25165824);
    float* ps = (float*)(ws + 25165824 + 4096000);
    float* pt = (float*)(ws + 25165824 + 8192000);
    float* pd = (float*)(ws + 25165824 + 12288000);
    float* tgtLogit = (float*)(ws + 41549824);
    float* scal = (float*)(ws + 41558016);

    hipMemsetAsync(scal, 0, 3 * sizeof(float), stream);

    {
      int n4 = BT * HS / 4;
      cvt_f32_bf16<<<(n4 + 255) / 256, 256, 0, stream>>>((const float4*)student, (u32x2*)sAb, n4);
    }
    {
      int n4 = BT * HT / 4;
      cvt_f32_bf16<<<(n4 + 255) / 256, 256, 0, stream>>>((const float4*)teacher, (u32x2*)tAb, n4);
    }

    kmain<false><<<dim3(4000), dim3(256), 0, stream>>>(
        sAb, tAb, (const void*)sW, (const void*)tW, target, pe, ps, pt, pd, tgtLogit);
    kreduce<<<dim3(8), dim3(256), 0, stream>>>(pe, ps, pt, pd, tgtLogit, target, scal);
    kfinal<<<dim3(1), dim3(1), 0, stream>>>(scal, out);
  }
}

// Round 2
// 1742.615 us; speedup vs baseline: 1.2477x; 1.2477x over previous
//
#include <hip/hip_runtime.h>
#include <hip/hip_bf16.h>
#include <stdint.h>

#define BT 2048
#define HS 2048      // student hidden (H/2)
#define HT 4096      // teacher hidden (H)
#define NVOCAB 32000
#define IGN (-100)

#define NTS (HS / 32)      // 64 student K-tiles
#define NTT (HT / 32)      // 128 teacher K-tiles
#define TOT (NTS + NTT)    // 192

typedef unsigned short u16;
typedef unsigned int u32;
typedef __attribute__((ext_vector_type(4))) float f32x4;
typedef __attribute__((ext_vector_type(8))) short short8;
typedef __attribute__((ext_vector_type(2))) unsigned int u32x2;
typedef __attribute__((ext_vector_type(4))) unsigned int u32x4;

// ---------- helpers ----------
__device__ inline u32 pack2_bf16(float a, float b) {
  union { __hip_bfloat162 h; u32 u; } cv;
  cv.h = __float22bfloat162_rn(make_float2(a, b));
  return cv.u;
}

__device__ inline void async16(const void* g, void* l) {
  __builtin_amdgcn_global_load_lds(
      (const __attribute__((address_space(1))) void*)g,
      (__attribute__((address_space(3))) void*)l, 16, 0, 0);
}

// ---------- fp32 -> bf16 convert (activations + weights prepass), 32B/lane ----------
__global__ void cvt_f32_bf16(const float4* __restrict__ in, u32x4* __restrict__ out, int n8) {
  int i = blockIdx.x * blockDim.x + threadIdx.x;
  if (i >= n8) return;
  float4 a = in[2 * i], b = in[2 * i + 1];
  u32x4 o;
  o.x = pack2_bf16(a.x, a.y);
  o.y = pack2_bf16(a.z, a.w);
  o.z = pack2_bf16(b.x, b.y);
  o.w = pack2_bf16(b.z, b.w);
  out[i] = o;
}

// ---------- fused dual-GEMM, 256x256 tile, 4-slot pipelined, counted vmcnt ----------
__global__ __launch_bounds__(512, 2) void kmain(
    const u16* __restrict__ sAb, const u16* __restrict__ tAb,
    const u16* __restrict__ sWb, const u16* __restrict__ tWb,
    const int* __restrict__ target,
    float* __restrict__ pe, float* __restrict__ ps,
    float* __restrict__ pt, float* __restrict__ pd,
    float* __restrict__ tgtLogit) {
  // [slot][op A=0/B=1][256 rows x 32 cols bf16 = 8192 u16 = 16KB]
  __shared__ u16 lds[4][2][8192];          // 128 KiB
  __shared__ int tgtLds[256];

  // ---- T1: bijective XCD swizzle; each XCD owns one 256-row activation panel ----
  const int bid = blockIdx.x;                   // 0..999 (1000 % 8 == 0)
  const int wgid = (bid & 7) * 125 + (bid >> 3);
  const int rb = wgid / 125;                    // 0..7
  const int cb = wgid % 125;                    // 0..124
  const int row0 = rb * 256;
  const int col0 = cb * 256;

  const int tid = threadIdx.x;
  const int lane = tid & 63;
  const int w = tid >> 6;        // wave 0..7
  const int wr = w >> 2;         // 0..1  (M)
  const int wc = w & 3;          // 0..3  (N)
  const int l15 = lane & 15;
  const int q = lane >> 4;
  const int q4 = q << 2;
  // T2 read-side swizzle: granule q' = q ^ ((l15>>1)&3), in u16 units (x8)
  const int qp8 = ((q ^ ((l15 >> 1) & 3)) << 3);

  if (tid < 256) tgtLds[tid] = target[row0 + tid];

  // staging constants: thread covers (row = w*32 + lane/4 [+16]), granule g' swizzled
  const int rowA = w * 32 + (lane >> 2);
  const int gp8 = (((lane & 3) ^ ((lane >> 3) & 3)) << 3);  // inverse-swz source granule
  const u32 offS = (u32)rowA * HS + gp8;
  const u32 offT = (u32)rowA * HT + gp8;
  const u16* baseAs = sAb + (size_t)row0 * HS;
  const u16* baseAt = tAb + (size_t)row0 * HT;
  const u16* baseBs = sWb + (size_t)col0 * HS;
  const u16* baseBt = tWb + (size_t)col0 * HT;
  const int wdst = w * 1024;   // per-wave LDS dest (u16) within a slot-operand

  f32x4 acc[8][4];
#pragma unroll
  for (int m = 0; m < 8; m++)
#pragma unroll
    for (int n = 0; n < 4; n++) acc[m][n] = (f32x4){0.f, 0.f, 0.f, 0.f};
  u32 stash[8][4][2];          // student logits, packed bf16, static-indexed only

  // ---- prologue: stage tiles 0..2 (all student; NTS >= 3) ----
#pragma unroll
  for (int t = 0; t < 3; t++) {
    const u16* pA = baseAs + offS + t * 32;
    async16(pA, &lds[t][0][wdst]);
    async16(pA + 16 * HS, &lds[t][0][wdst + 512]);
    const u16* pB = baseBs + offS + t * 32;
    async16(pB, &lds[t][1][wdst]);
    async16(pB + 16 * HS, &lds[t][1][wdst + 512]);
  }
  asm volatile("s_waitcnt lgkmcnt(0)" ::: "memory");  // tgtLds write visible
  __builtin_amdgcn_s_barrier();
  __builtin_amdgcn_sched_barrier(0);

  for (int T = 0; T < TOT; T++) {
    const int slot = T & 3;
    const int slotP = (T + 3) & 3;   // == (T-1)&3: WAR-safe (reads done before prev barrier)
    // source select for prefetched tile
    const int Tp = (T + 3 < TOT) ? T + 3 : TOT - 1;   // tail clamp: redundant, never read
    const u16 *bA, *bB;
    u32 off;
    int ld16, k0;
    if (Tp < NTS) { bA = baseAs; bB = baseBs; off = offS; ld16 = 16 * HS; k0 = Tp * 32; }
    else          { bA = baseAt; bB = baseBt; off = offT; ld16 = 16 * HT; k0 = (Tp - NTS) * 32; }

    // tile T's 4 loads are the oldest of 12 outstanding -> counted wait, never 0
    asm volatile("s_waitcnt vmcnt(8)" ::: "memory");
    __builtin_amdgcn_s_barrier();
    __builtin_amdgcn_sched_barrier(0);

    const u16* sA = &lds[slot][0][0];
    const u16* sB = &lds[slot][1][0];

    // ---- phase 0: frag reads + A-prefetch + 16 MFMA (m0..3) ----
    short8 bf[4], af[4];
#pragma unroll
    for (int n = 0; n < 4; n++)
      bf[n] = *(const short8*)&sB[(wc * 64 + n * 16 + l15) * 32 + qp8];
#pragma unroll
    for (int m = 0; m < 4; m++)
      af[m] = *(const short8*)&sA[(wr * 128 + m * 16 + l15) * 32 + qp8];
    {
      const u16* p = bA + off + k0;
      async16(p, &lds[slotP][0][wdst]);
      async16(p + ld16, &lds[slotP][0][wdst + 512]);
    }
    __builtin_amdgcn_s_setprio(1);
#pragma unroll
    for (int m = 0; m < 4; m++)
#pragma unroll
      for (int n = 0; n < 4; n++)
        acc[m][n] = __builtin_amdgcn_mfma_f32_16x16x32_bf16(af[m], bf[n], acc[m][n], 0, 0, 0);
    __builtin_amdgcn_s_setprio(0);
    __builtin_amdgcn_s_barrier();
    __builtin_amdgcn_sched_barrier(0);

    // ---- phase 1: frag reads + B-prefetch + 16 MFMA (m4..7) ----
#pragma unroll
    for (int m = 0; m < 4; m++)
      af[m] = *(const short8*)&sA[(wr * 128 + (m + 4) * 16 + l15) * 32 + qp8];
    {
      const u16* p = bB + off + k0;
      async16(p, &lds[slotP][1][wdst]);
      async16(p + ld16, &lds[slotP][1][wdst + 512]);
    }
    __builtin_amdgcn_s_setprio(1);
#pragma unroll
    for (int m = 0; m < 4; m++)
#pragma unroll
      for (int n = 0; n < 4; n++)
        acc[m + 4][n] = __builtin_amdgcn_mfma_f32_16x16x32_bf16(af[m], bf[n], acc[m + 4][n], 0, 0, 0);
    __builtin_amdgcn_s_setprio(0);
    __builtin_amdgcn_s_barrier();
    __builtin_amdgcn_sched_barrier(0);

    if (T == NTS - 1) {
      // ===== epilogue 1: expsum, sumsq_s, target logit, stash s in regs =====
#pragma unroll
      for (int m = 0; m < 8; m++) {
        float se[4] = {0.f, 0.f, 0.f, 0.f}, sq[4] = {0.f, 0.f, 0.f, 0.f};
        const int rloc = wr * 128 + m * 16 + q4;
#pragma unroll
        for (int n = 0; n < 4; n++) {
          f32x4 v = acc[m][n];
          stash[m][n][0] = pack2_bf16(v[0], v[1]);
          stash[m][n][1] = pack2_bf16(v[2], v[3]);
          const int cGlob = col0 + wc * 64 + n * 16 + l15;
#pragma unroll
          for (int rg = 0; rg < 4; rg++) {
            float x = v[rg];
            se[rg] += __expf(x);
            sq[rg] += x * x;
            if (tgtLds[rloc + rg] == cGlob) tgtLogit[row0 + rloc + rg] = x;
          }
          acc[m][n] = (f32x4){0.f, 0.f, 0.f, 0.f};
        }
#pragma unroll
        for (int msk = 1; msk < 16; msk <<= 1) {
#pragma unroll
          for (int rg = 0; rg < 4; rg++) {
            se[rg] += __shfl_xor(se[rg], msk, 64);
            sq[rg] += __shfl_xor(sq[rg], msk, 64);
          }
        }
        if (l15 == 0) {
          size_t pbase = (size_t)(cb * 4 + wc) * BT + row0 + rloc;
#pragma unroll
          for (int rg = 0; rg < 4; rg++) { pe[pbase + rg] = se[rg]; ps[pbase + rg] = sq[rg]; }
        }
      }
      // drain stores so the counted-vmcnt invariant stays exact
      asm volatile("s_waitcnt vmcnt(0)" ::: "memory");
    }
  }

  // ===== epilogue 2: sumsq_t, dot(s,t) =====
#pragma unroll
  for (int m = 0; m < 8; m++) {
    float st[4] = {0.f, 0.f, 0.f, 0.f}, dt[4] = {0.f, 0.f, 0.f, 0.f};
    const int rloc = wr * 128 + m * 16 + q4;
#pragma unroll
    for (int n = 0; n < 4; n++) {
      f32x4 v = acc[m][n];
      float sv[4];
      sv[0] = __uint_as_float(stash[m][n][0] << 16);
      sv[1] = __uint_as_float(stash[m][n][0] & 0xffff0000u);
      sv[2] = __uint_as_float(stash[m][n][1] << 16);
      sv[3] = __uint_as_float(stash[m][n][1] & 0xffff0000u);
#pragma unroll
      for (int rg = 0; rg < 4; rg++) {
        float t = v[rg];
        st[rg] += t * t;
        dt[rg] += sv[rg] * t;
      }
    }
#pragma unroll
    for (int msk = 1; msk < 16; msk <<= 1) {
#pragma unroll
      for (int rg = 0; rg < 4; rg++) {
        st[rg] += __shfl_xor(st[rg], msk, 64);
        dt[rg] += __shfl_xor(dt[rg], msk, 64);
      }
    }
    if (l15 == 0) {
      size_t pbase = (size_t)(cb * 4 + wc) * BT + row0 + rloc;
#pragma unroll
      for (int rg = 0; rg < 4; rg++) { pt[pbase + rg] = st[rg]; pd[pbase + rg] = dt[rg]; }
    }
  }
}

// ---------- two-stage per-row reduce over 500 column slabs ----------
__global__ void kreduce1(const float* __restrict__ pe, const float* __restrict__ ps,
                         const float* __restrict__ pt, const float* __restrict__ pd,
                         float* __restrict__ part) {
  int row = blockIdx.x * 256 + threadIdx.x;   // 8 x-blocks
  int c = blockIdx.y;                          // 25 chunks of 20 slabs
  float a = 0.f, b = 0.f, cc = 0.f, d = 0.f;
  int j0 = c * 20;
  for (int j = j0; j < j0 + 20; j++) {
    int idx = j * BT + row;
    a += pe[idx]; b += ps[idx]; cc += pt[idx]; d += pd[idx];
  }
  int o = c * BT + row;
  part[o] = a;
  part[25 * BT + o] = b;
  part[50 * BT + o] = cc;
  part[75 * BT + o] = d;
}

__global__ void kreduce2(const float* __restrict__ part, const float* __restrict__ tgtLogit,
                         const int* __restrict__ target, float* __restrict__ scal) {
  int row = blockIdx.x * 256 + threadIdx.x;   // 8 blocks -> 2048 rows
  float se = 0.f, ss = 0.f, st = 0.f, dt = 0.f;
  for (int c = 0; c < 25; c++) {
    int o = c * BT + row;
    se += part[o];
    ss += part[25 * BT + o];
    st += part[50 * BT + o];
    dt += part[75 * BT + o];
  }
  int tgt = target[row];
  bool valid = (tgt != IGN);
  float hard = valid ? (__logf(se) - tgtLogit[row]) : 0.f;
  float cosv = dt * rsqrtf(ss + 1e-12f) * rsqrtf(st + 1e-12f);
  float soft = 1.f - cosv;
  float nv = valid ? 1.f : 0.f;
  for (int m = 1; m < 64; m <<= 1) {
    hard += __shfl_xor(hard, m, 64);
    soft += __shfl_xor(soft, m, 64);
    nv += __shfl_xor(nv, m, 64);
  }
  if ((threadIdx.x & 63) == 0) {
    atomicAdd(&scal[0], hard);
    atomicAdd(&scal[1], soft);
    atomicAdd(&scal[2], nv);
  }
}

__global__ void kfinal(const float* __restrict__ scal, float* __restrict__ out) {
  float nv = scal[2];
  out[0] = 0.5f * scal[0] / nv + 0.5f * scal[1] / nv;
}

// ---------- launch ----------
extern "C" void kernel_launch(void* const* d_in, const int* in_sizes, int n_in,
                              void* d_out, int out_size, void* d_ws, size_t ws_size,
                              hipStream_t stream) {
  const float* student = (const float*)d_in[0];
  const float* teacher = (const float*)d_in[1];
  const int* target = (const int*)d_in[2];
  const float* sW = (const float*)d_in[3];
  const float* tW = (const float*)d_in[4];
  float* out = (float*)d_out;

  char* ws = (char*)d_ws;
  // layout (bytes) — unchanged total vs verified round:
  //   sAb : 0           (2048x2048 bf16 =   8,388,608)
  //   tAb : 8,388,608   (2048x4096 bf16 =  16,777,216)
  //   sWb : 25,165,824  (32000x2048 bf16 = 131,072,000)
  //   tWb : 156,237,824 (32000x4096 bf16 = 262,144,000)
  //   pe/ps/pt/pd : 4 x 4,096,000 at 418,381,824
  //   tgtLogit : 434,765,824 (2048 f32)
  //   scal : 434,774,016 (3 f32)
  //   part : overlaps dead sAb (ws+0) — used only after kmain
  u16* sAb = (u16*)(ws);
  u16* tAb = (u16*)(ws + 8388608);
  u16* sWb = (u16*)(ws + 25165824);
  u16* tWb = (u16*)(ws + 156237824);
  float* pe = (float*)(ws + 418381824);
  float* ps = (float*)(ws + 422477824);
  float* pt = (float*)(ws + 426573824);
  float* pd = (float*)(ws + 430669824);
  float* tgtLogit = (float*)(ws + 434765824);
  float* scal = (float*)(ws + 434774016);
  float* part = (float*)(ws);   // 819,200 B scratch, reuses dead sAb region

  hipMemsetAsync(scal, 0, 3 * sizeof(float), stream);

  {
    int n8 = BT * HS / 8;
    cvt_f32_bf16<<<(n8 + 255) / 256, 256, 0, stream>>>((const float4*)student, (u32x4*)sAb, n8);
  }
  {
    int n8 = BT * HT / 8;
    cvt_f32_bf16<<<(n8 + 255) / 256, 256, 0, stream>>>((const float4*)teacher, (u32x4*)tAb, n8);
  }
  {
    int n8 = NVOCAB * HS / 8;
    cvt_f32_bf16<<<(n8 + 255) / 256, 256, 0, stream>>>((const float4*)sW, (u32x4*)sWb, n8);
  }
  {
    int n8 = NVOCAB * HT / 8;
    cvt_f32_bf16<<<(n8 + 255) / 256, 256, 0, stream>>>((const float4*)tW, (u32x4*)tWb, n8);
  }

  kmain<<<dim3(1000), dim3(512), 0, stream>>>(sAb, tAb, sWb, tWb, target,
                                              pe, ps, pt, pd, tgtLogit);
  kreduce1<<<dim3(8, 25), dim3(256), 0, stream>>>(pe, ps, pt, pd, part);
  kreduce2<<<dim3(8), dim3(256), 0, stream>>>(part, tgtLogit, target, scal);
  kfinal<<<dim3(1), dim3(1), 0, stream>>>(scal, out);
}